// Round 1
// 184.940 us; speedup vs baseline: 1.0076x; 1.0076x over previous
//
#include <hip/hip_runtime.h>

// Attention: B=256,H=16,NQ=NK=49,D=64, fp32 in/out. One block per (b,h).
// R5 = R4 + occupancy push (theory: latency-bound, MfmaUtil 2%, VALU 12%,
// HBM 22%, occ 42% -> nothing saturated; LDS 27.6KB capped us at 5 blocks/CU).
//  - Q staging buffer removed: Q fragment rows are wave-private, loaded
//    straight from global into registers (scale folded in).
//  - P aliases Ks (not Qs) behind a second barrier; P rows are wave-private
//    so no barrier needed between P-write and P-read.
//  - LDS: 2 x 64*72*2B = 18432 B -> 8 blocks/CU; __launch_bounds__(256,8).
// Kept from R4: ST=72 stride (2-way-max bank aliasing on b128 frag reads),
// XOR-swizzled Vt transpose with UNCONDITIONAL zero-fill pad rows (NaN fix),
// no max-subtract softmax (s bounded), masked pad cols k=49..63.

#define NQA 49
#define DD  64
#define ST  72   // LDS row stride (bf16 elems); 144 B keeps b128 reads aligned.

typedef __bf16 bf16x4 __attribute__((ext_vector_type(4)));
typedef __bf16 bf16x8 __attribute__((ext_vector_type(8)));
typedef float  f32x4  __attribute__((ext_vector_type(4)));

// Swizzled Vt offset for logical (d, k): k's group-of-8 rotated by (d>>2)&7.
__device__ __forceinline__ int vt_off(int d, int k) {
    return d * ST + ((((k >> 3) + ((d >> 2) & 7)) & 7) << 3) + (k & 7);
}

__global__ __launch_bounds__(256, 8)
void attn49_kernel(const float* __restrict__ Q, const float* __restrict__ K,
                   const float* __restrict__ V, float* __restrict__ O) {
    __shared__ __bf16 KPs[64 * ST];  // K rows (phase 1), then P rows (phase 2)
    __shared__ __bf16 Vt[64 * ST];   // swizzled V^T: (d,k) at vt_off

    const int tid = threadIdx.x;
    const size_t base = (size_t)blockIdx.x * (NQA * DD);
    const float* Kg = K + base;
    const float* Vg = V + base;

    // ---- coalesced staging of K and V only ----
    {
        const int f  = tid & 15;   // float4 index within a 64-float row
        const int r0 = tid >> 4;   // 0..15
        #pragma unroll
        for (int it = 0; it < 4; ++it) {
            const int r = r0 + 16 * it;       // 0..63
            float4 kv = {0.f,0.f,0.f,0.f}, vv = {0.f,0.f,0.f,0.f};
            if (r < NQA) {
                kv = *(const float4*)(Kg + r * DD + 4 * f);
                vv = *(const float4*)(Vg + r * DD + 4 * f);
            }
            bf16x4 kb = { (__bf16)kv.x, (__bf16)kv.y, (__bf16)kv.z, (__bf16)kv.w };
            *(bf16x4*)&KPs[r * ST + 4 * f] = kb;
            // transpose: V[r][4f+j] -> Vt[d=4f+j][k=r]; UNCONDITIONAL so pad
            // cols k=49..63 are zeros, not LDS garbage (NaN poison in MFMA).
            Vt[vt_off(4*f + 0, r)] = (__bf16)vv.x;
            Vt[vt_off(4*f + 1, r)] = (__bf16)vv.y;
            Vt[vt_off(4*f + 2, r)] = (__bf16)vv.z;
            Vt[vt_off(4*f + 3, r)] = (__bf16)vv.w;
        }
    }

    const int w  = tid >> 6;        // wave 0..3 owns S/O rows 16w..16w+15
    const int lr = tid & 15;
    const int lg = (tid >> 4) & 3;  // quad

    // ---- Q fragments straight from global (rows are wave-private) ----
    bf16x8 aq0, aq1;
    {
        const int qrow = 16*w + lr;
        float4 qa = {0.f,0.f,0.f,0.f}, qb = {0.f,0.f,0.f,0.f},
               qc = {0.f,0.f,0.f,0.f}, qd = {0.f,0.f,0.f,0.f};
        if (qrow < NQA) {
            const float* Qr = Q + base + (size_t)qrow * DD + 8 * lg;
            qa = *(const float4*)(Qr +  0);   // cols 8lg   .. 8lg+3
            qb = *(const float4*)(Qr +  4);   // cols 8lg+4 .. 8lg+7
            qc = *(const float4*)(Qr + 32);   // cols 32+8lg .. +3
            qd = *(const float4*)(Qr + 36);   // cols 32+8lg+4 .. +7
        }
        // scale 1/sqrt(64) folded into the bf16 convert
        aq0 = bf16x8{ (__bf16)(0.125f*qa.x), (__bf16)(0.125f*qa.y),
                      (__bf16)(0.125f*qa.z), (__bf16)(0.125f*qa.w),
                      (__bf16)(0.125f*qb.x), (__bf16)(0.125f*qb.y),
                      (__bf16)(0.125f*qb.z), (__bf16)(0.125f*qb.w) };
        aq1 = bf16x8{ (__bf16)(0.125f*qc.x), (__bf16)(0.125f*qc.y),
                      (__bf16)(0.125f*qc.z), (__bf16)(0.125f*qc.w),
                      (__bf16)(0.125f*qd.x), (__bf16)(0.125f*qd.y),
                      (__bf16)(0.125f*qd.z), (__bf16)(0.125f*qd.w) };
    }
    __syncthreads();   // barrier 1: K/Vt staged

    // ---- phase 1: S = (Q*scale) K^T ----
    f32x4 acc[4] = {};
    #pragma unroll
    for (int t = 0; t < 4; ++t) {
        bf16x8 b0 = *(const bf16x8*)&KPs[(16*t + lr) * ST      + 8*lg];
        bf16x8 b1 = *(const bf16x8*)&KPs[(16*t + lr) * ST + 32 + 8*lg];
        acc[t] = __builtin_amdgcn_mfma_f32_16x16x32_bf16(aq0, b0, acc[t], 0, 0, 0);
        acc[t] = __builtin_amdgcn_mfma_f32_16x16x32_bf16(aq1, b1, acc[t], 0, 0, 0);
    }

    __syncthreads();   // barrier 2: all K fragment reads retired before P
                       // overwrites the same LDS region.

    // ---- softmax (no max-subtract; s bounded ~±6). Lane: rows 16w+4lg+i,
    //      col 16t+lr. K pad rows are zero => mask cols 49..63.
    float inv_l[4];
    #pragma unroll
    for (int i = 0; i < 4; ++i) {
        const int gq = 16*w + 4*lg + i;
        float e0 = __expf(acc[0][i]);
        float e1 = __expf(acc[1][i]);
        float e2 = __expf(acc[2][i]);
        float e3 = (lr == 0) ? __expf(acc[3][i]) : 0.f;  // cols 49..63 masked
        float sum = (e0 + e1) + (e2 + e3);
        #pragma unroll
        for (int d = 1; d < 16; d <<= 1) sum += __shfl_xor(sum, d, 64);
        inv_l[i] = 1.f / (sum + 1e-9f);
        // P rows are wave-private (alias onto KPs; this wave re-reads only
        // its own 16 rows, which it fully rewrites here)
        KPs[gq * ST +  0 + lr] = (__bf16)e0;
        KPs[gq * ST + 16 + lr] = (__bf16)e1;
        KPs[gq * ST + 32 + lr] = (__bf16)e2;
        KPs[gq * ST + 48 + lr] = (__bf16)e3;
    }

    // ---- phase 2: O = P * V (B-frags from swizzled Vt, contiguous b128) ----
    bf16x8 ap0 = *(const bf16x8*)&KPs[(16*w + lr) * ST      + 8*lg];
    bf16x8 ap1 = *(const bf16x8*)&KPs[(16*w + lr) * ST + 32 + 8*lg];
    f32x4 oacc[4] = {};
    #pragma unroll
    for (int t = 0; t < 4; ++t) {
        bf16x8 b0 = *(const bf16x8*)&Vt[vt_off(16*t + lr,  8*lg)];
        bf16x8 b1 = *(const bf16x8*)&Vt[vt_off(16*t + lr, 32 + 8*lg)];
        oacc[t] = __builtin_amdgcn_mfma_f32_16x16x32_bf16(ap0, b0, oacc[t], 0, 0, 0);
        oacc[t] = __builtin_amdgcn_mfma_f32_16x16x32_bf16(ap1, b1, oacc[t], 0, 0, 0);
    }

    // ---- epilogue: scale by 1/(l+eps), store fp32 (coalesced 16-lane runs) ----
    float* Og = O + base;
    #pragma unroll
    for (int i = 0; i < 4; ++i) {
        const int gq = 16*w + 4*lg + i;
        if (gq < NQA) {
            #pragma unroll
            for (int t = 0; t < 4; ++t)
                Og[gq * DD + 16*t + lr] = oacc[t][i] * inv_l[i];
        }
    }
}

extern "C" void kernel_launch(void* const* d_in, const int* in_sizes, int n_in,
                              void* d_out, int out_size, void* d_ws, size_t ws_size,
                              hipStream_t stream) {
    const float* q = (const float*)d_in[0];
    const float* k = (const float*)d_in[1];
    const float* v = (const float*)d_in[2];
    float* out = (float*)d_out;
    (void)in_sizes; (void)n_in; (void)out_size; (void)d_ws; (void)ws_size;
    attn49_kernel<<<dim3(4096), dim3(256), 0, stream>>>(q, k, v, out);
}